// Round 6
// baseline (122.013 us; speedup 1.0000x reference)
//
#include <hip/hip_runtime.h>
#include <stdint.h>

// Problem constants (fixed by setup_inputs): B=32, N=512, D=512
#define BATCH 32
#define NDIM 512
#define DDIM 512
#define XELEMS (BATCH * NDIM * DDIM)   // 8388608
#define WELEMS (DDIM * DDIM)           // 262144
#define KITERS (DDIM / 64)             // 8
#define LDA 72                         // padded LDS row stride (fp16): 144B breaks b128 bank aliasing

typedef _Float16 f16x8 __attribute__((ext_vector_type(8)));
typedef float f32x4 __attribute__((ext_vector_type(4)));

__device__ __forceinline__ f16x8 cvt8(float4 a, float4 b) {
    f16x8 h;
    h[0] = (_Float16)a.x; h[1] = (_Float16)a.y; h[2] = (_Float16)a.z; h[3] = (_Float16)a.w;
    h[4] = (_Float16)b.x; h[5] = (_Float16)b.y; h[6] = (_Float16)b.z; h[7] = (_Float16)b.w;
    return h;
}

// ---------------- pass 0 (tiny): W fp32 -> Wt fp16 transpose (1.5 MB traffic) -------
__global__ __launch_bounds__(256) void transpose_w(const float* __restrict__ W,
                                                   _Float16* __restrict__ Wt) {
    __shared__ float tile[32][33];
    int bx = blockIdx.x;              // e-tile
    int by = blockIdx.y;              // d-tile
    int tx = threadIdx.x & 31;
    int ty = threadIdx.x >> 5;        // 0..7
    for (int r = ty; r < 32; r += 8)
        tile[r][tx] = W[(by * 32 + r) * DDIM + bx * 32 + tx];
    __syncthreads();
    for (int r = ty; r < 32; r += 8)
        Wt[(size_t)(bx * 32 + r) * DDIM + by * 32 + tx] = (_Float16)tile[tx][r];
}

// ---------------- GEMM1: Y = X(fp32, 16384x512) @ Wt^T(fp16) -> fp16 Y --------------
// X is converted fp32->fp16 DURING staging (register-stage + cvt + ds_write) —
// the separate conversion pass over X (51 MB) is deleted.
// 128x64 tile, BK=64, register-staged K-pipeline (loads for tile k+1 issued before
// compute of tile k; vmcnt drains a full compute-phase later, at next ds_write).
// Grid 1024, XCD-affine: blk%8 = m%8 so the 8 n-tiles sharing an X-panel share an XCD.
__global__ __launch_bounds__(256) void gemm_xw(const float* __restrict__ X,
                                               const _Float16* __restrict__ Wt,
                                               _Float16* __restrict__ Y) {
    __shared__ __align__(16) _Float16 As[128 * LDA];   // 18 KB
    __shared__ __align__(16) _Float16 Bs[64 * LDA];    //  9 KB

    const int tid  = threadIdx.x;
    const int lane = tid & 63;
    const int wv   = tid >> 6;

    const int blk = blockIdx.x;
    const int n0 = (blk >> 7) * 64;
    const int m0 = (blk & 127) * 128;

    const int lr = lane >> 3;          // row within 8-row chunk
    const int lc = lane & 7;           // 16B fp16 slot / 8-col group

    // A: 16 chunks (8 rows x 64 cols), wave owns 4. Source fp32: 2 float4 per lane.
    const float* ga[4];
    int la[4];
#pragma unroll
    for (int t = 0; t < 4; ++t) {
        int row = (wv * 4 + t) * 8 + lr;
        ga[t] = X + (size_t)(m0 + row) * DDIM + lc * 8;
        la[t] = row * LDA + lc * 8;
    }
    // B: 8 chunks of Wt (fp16), wave owns 2.
    const _Float16* gb[2];
    int lb[2];
#pragma unroll
    for (int t = 0; t < 2; ++t) {
        int row = (wv * 2 + t) * 8 + lr;
        gb[t] = Wt + (size_t)(n0 + row) * DDIM + lc * 8;
        lb[t] = row * LDA + lc * 8;
    }

    const int quad = lane >> 4;
    const int l16  = lane & 15;

    f32x4 acc[2][4];
#pragma unroll
    for (int i = 0; i < 2; ++i)
#pragma unroll
        for (int j = 0; j < 4; ++j)
            acc[i][j] = (f32x4){0.f, 0.f, 0.f, 0.f};

    // prologue: tile 0 into regs
    float4 raa[4], rab[4];
    f16x8 rb[2];
#pragma unroll
    for (int t = 0; t < 4; ++t) {
        raa[t] = *(const float4*)(ga[t]);
        rab[t] = *(const float4*)(ga[t] + 4);
    }
#pragma unroll
    for (int t = 0; t < 2; ++t) rb[t] = *(const f16x8*)gb[t];

#pragma unroll
    for (int it = 0; it < KITERS; ++it) {
        if (it > 0) __syncthreads();
        // commit staged regs (cvt fp32->fp16 for A)
#pragma unroll
        for (int t = 0; t < 4; ++t) *(f16x8*)&As[la[t]] = cvt8(raa[t], rab[t]);
#pragma unroll
        for (int t = 0; t < 2; ++t) *(f16x8*)&Bs[lb[t]] = rb[t];
        __syncthreads();

        if (it + 1 < KITERS) {
            const int k1 = (it + 1) * 64;
#pragma unroll
            for (int t = 0; t < 4; ++t) {
                raa[t] = *(const float4*)(ga[t] + k1);
                rab[t] = *(const float4*)(ga[t] + k1 + 4);
            }
#pragma unroll
            for (int t = 0; t < 2; ++t) rb[t] = *(const f16x8*)(gb[t] + k1);
        }

#pragma unroll
        for (int kkc = 0; kkc < 8; kkc += 4) {
            const int pa = (kkc + quad) * 8;
            f16x8 a0 = *(const f16x8*)&As[(wv * 32 +      l16) * LDA + pa];
            f16x8 a1 = *(const f16x8*)&As[(wv * 32 + 16 + l16) * LDA + pa];
#pragma unroll
            for (int nt = 0; nt < 4; ++nt) {
                f16x8 b = *(const f16x8*)&Bs[(nt * 16 + l16) * LDA + pa];
                acc[0][nt] = __builtin_amdgcn_mfma_f32_16x16x32_f16(a0, b, acc[0][nt], 0, 0, 0);
                acc[1][nt] = __builtin_amdgcn_mfma_f32_16x16x32_f16(a1, b, acc[1][nt], 0, 0, 0);
            }
        }
    }

    // epilogue: fp16 Y. C/D layout: col = lane&15, row = quad*4 + reg.
#pragma unroll
    for (int mt = 0; mt < 2; ++mt)
#pragma unroll
        for (int nt = 0; nt < 4; ++nt)
#pragma unroll
            for (int r = 0; r < 4; ++r) {
                int gi = m0 + wv * 32 + mt * 16 + quad * 4 + r;
                int gj = n0 + nt * 16 + l16;
                Y[(size_t)gi * DDIM + gj] = (_Float16)acc[mt][nt][r];
            }
}

// ---------------- GEMM2: S_b = Y_b(fp16) @ X_b^T(fp32, cvt on stage) + bias, diag=0 -
// Grid 1024, blk%8 = batch%8: batch's Y_b + X_b pinned to one XCD's L2.
__global__ __launch_bounds__(256) void gemm_yx(const _Float16* __restrict__ Y,
                                               const float* __restrict__ X,
                                               float* __restrict__ Sout,
                                               const float* __restrict__ bias_ptr) {
    __shared__ __align__(16) _Float16 As[128 * LDA];
    __shared__ __align__(16) _Float16 Bs[64 * LDA];

    const int tid  = threadIdx.x;
    const int lane = tid & 63;
    const int wv   = tid >> 6;

    const int blk = blockIdx.x;
    const int batch = blk & 31;
    const int t2 = blk >> 5;
    const int n0 = (t2 & 7) * 64;
    const int m0 = (t2 >> 3) * 128;

    const _Float16* Ab = Y + (size_t)batch * (NDIM * DDIM);
    const float*    Bb = X + (size_t)batch * (NDIM * DDIM);

    const int lr = lane >> 3;
    const int lc = lane & 7;

    const _Float16* ga[4];
    int la[4];
#pragma unroll
    for (int t = 0; t < 4; ++t) {
        int row = (wv * 4 + t) * 8 + lr;
        ga[t] = Ab + (size_t)(m0 + row) * DDIM + lc * 8;
        la[t] = row * LDA + lc * 8;
    }
    const float* gb[2];
    int lb[2];
#pragma unroll
    for (int t = 0; t < 2; ++t) {
        int row = (wv * 2 + t) * 8 + lr;
        gb[t] = Bb + (size_t)(n0 + row) * DDIM + lc * 8;
        lb[t] = row * LDA + lc * 8;
    }

    const int quad = lane >> 4;
    const int l16  = lane & 15;

    f32x4 acc[2][4];
#pragma unroll
    for (int i = 0; i < 2; ++i)
#pragma unroll
        for (int j = 0; j < 4; ++j)
            acc[i][j] = (f32x4){0.f, 0.f, 0.f, 0.f};

    f16x8 ra[4];
    float4 rba[2], rbb[2];
#pragma unroll
    for (int t = 0; t < 4; ++t) ra[t] = *(const f16x8*)ga[t];
#pragma unroll
    for (int t = 0; t < 2; ++t) {
        rba[t] = *(const float4*)(gb[t]);
        rbb[t] = *(const float4*)(gb[t] + 4);
    }

#pragma unroll
    for (int it = 0; it < KITERS; ++it) {
        if (it > 0) __syncthreads();
#pragma unroll
        for (int t = 0; t < 4; ++t) *(f16x8*)&As[la[t]] = ra[t];
#pragma unroll
        for (int t = 0; t < 2; ++t) *(f16x8*)&Bs[lb[t]] = cvt8(rba[t], rbb[t]);
        __syncthreads();

        if (it + 1 < KITERS) {
            const int k1 = (it + 1) * 64;
#pragma unroll
            for (int t = 0; t < 4; ++t) ra[t] = *(const f16x8*)(ga[t] + k1);
#pragma unroll
            for (int t = 0; t < 2; ++t) {
                rba[t] = *(const float4*)(gb[t] + k1);
                rbb[t] = *(const float4*)(gb[t] + k1 + 4);
            }
        }

#pragma unroll
        for (int kkc = 0; kkc < 8; kkc += 4) {
            const int pa = (kkc + quad) * 8;
            f16x8 a0 = *(const f16x8*)&As[(wv * 32 +      l16) * LDA + pa];
            f16x8 a1 = *(const f16x8*)&As[(wv * 32 + 16 + l16) * LDA + pa];
#pragma unroll
            for (int nt = 0; nt < 4; ++nt) {
                f16x8 b = *(const f16x8*)&Bs[(nt * 16 + l16) * LDA + pa];
                acc[0][nt] = __builtin_amdgcn_mfma_f32_16x16x32_f16(a0, b, acc[0][nt], 0, 0, 0);
                acc[1][nt] = __builtin_amdgcn_mfma_f32_16x16x32_f16(a1, b, acc[1][nt], 0, 0, 0);
            }
        }
    }

    const float bias = bias_ptr[0];
#pragma unroll
    for (int mt = 0; mt < 2; ++mt)
#pragma unroll
        for (int nt = 0; nt < 4; ++nt)
#pragma unroll
            for (int r = 0; r < 4; ++r) {
                int gi = m0 + wv * 32 + mt * 16 + quad * 4 + r;
                int gj = n0 + nt * 16 + l16;
                float v = acc[mt][nt][r] + bias;
                if (gi == gj) v = 0.f;
                Sout[((size_t)batch * NDIM + gi) * NDIM + gj] = v;
            }
}

extern "C" void kernel_launch(void* const* d_in, const int* in_sizes, int n_in,
                              void* d_out, int out_size, void* d_ws, size_t ws_size,
                              hipStream_t stream) {
    const float* X  = (const float*)d_in[0];   // (32, 512, 512) fp32
    const float* W  = (const float*)d_in[1];   // (512, 512) fp32
    const float* bp = (const float*)d_in[2];   // scalar fp32
    float* out = (float*)d_out;                // (32, 512, 512) fp32

    // workspace layout (fp16): Wt[262144] | Y[8388608]   (Xh eliminated)
    _Float16* Wt = (_Float16*)d_ws;
    _Float16* Y  = Wt + WELEMS;

    // pass 0 (tiny): W transpose to fp16
    transpose_w<<<dim3(16, 16), 256, 0, stream>>>(W, Wt);

    // pass 1: Y = X @ Wt^T (X converted during staging)
    gemm_xw<<<1024, 256, 0, stream>>>(X, Wt, Y);

    // pass 2: S_b = Y_b @ X_b^T + bias, diag=0 (X converted during staging)
    gemm_yx<<<1024, 256, 0, stream>>>(Y, X, out, bp);

    (void)in_sizes; (void)n_in; (void)out_size; (void)ws_size;
}